// Round 7
// baseline (5404.685 us; speedup 1.0000x reference)
//
#include <hip/hip_runtime.h>

// ---------------- problem constants ----------------
#define T_SEQ 512
#define P_PRED 32
#define TP 544            // T_SEQ + P_PRED
#define BATCH 256
#define H 512
#define G4H 2048
// ---------------- kernel config --------------------
// ROUND-7 = ROUND-5 + per-wave flags (flags back at agent scope/LIC; r6's
// SC0 flags are unsound across dispatches: stale L2 flag lines from the
// previous launch false-pass the waits). 16 row-groups of 16 rows; group g
// on XCD g&7 (r4/r5-validated). 256 WGs = 8 XCDs x 32 slots; WG serves
// groups xcd and xcd+8 per round: waitA,bodyA,sigA,waitB,bodyB,sigB.
// NEW: flags are per-WAVE [group][slot*4+w] (128/group). Signal = per-wave
// s_waitcnt(0) drain + lane0 flag store, NO __syncthreads. Wait = every
// wave polls 2 flags/lane + ballot, NO trailing __syncthreads. The only
// WG sync per phase is the staging barrier inside do_phase16. Sound:
// entering phase p requires all 128 wave-flags >= p, and a wave's flag
// follows its LDS reads -> no staging-buffer overwrite hazard; all barrier
// instances stay phase-aligned. Data at SC0 (XCD L2), flags agent (LIC).
// Tripwires: absmax fail -> revert to r5; FETCH>=1GB -> r1 anomaly.
#define GRID 256
#define BLOCK 256
#define RPG 16              // rows per group
#define HBUF (BATCH*H)      // elements per h double-buffer slot
#define HBYTES (HBUF*2)
#define SCX 1               // CPol: SC0 -> bypass L1, coherent at XCD L2

typedef _Float16 half8 __attribute__((ext_vector_type(8)));
typedef float floatx4 __attribute__((ext_vector_type(4)));
typedef __amdgpu_buffer_rsrc_t rsrc_t;

#define MFMA(a,b,c) __builtin_amdgcn_mfma_f32_16x16x32_f16((a),(b),(c),0,0,0)

// ---------------- device-global state --------------
__device__ __attribute__((aligned(128))) _Float16 g_h1[2*HBUF];
__device__ __attribute__((aligned(128))) _Float16 g_h2[2*HBUF];
// o partials: [j = g*128 + slot*4 + w][t][32 slots (16 rows + 16 zero-fill)]
__device__ __attribute__((aligned(128))) float g_opart[(size_t)2048*TP*32];
__device__ __attribute__((aligned(128))) float g_seqT[T_SEQ*BATCH];  // [t][row]
__device__ __attribute__((aligned(128))) unsigned g_flags[16*128];   // per-wave

__device__ __forceinline__ rsrc_t mkrsrc(void* p){
  return __builtin_amdgcn_make_buffer_rsrc(p, (short)0, -1, 0x00020000);
}
__device__ __forceinline__ half8 ld_h8(rsrc_t r, int off){
  auto v = __builtin_amdgcn_raw_buffer_load_b128(r, off, 0, SCX);
  return __builtin_bit_cast(half8, v);
}
__device__ __forceinline__ floatx4 ld_f4(rsrc_t r, int off){
  auto v = __builtin_amdgcn_raw_buffer_load_b128(r, off, 0, SCX);
  return __builtin_bit_cast(floatx4, v);
}
__device__ __forceinline__ float ld_f(rsrc_t r, int off){
  auto v = __builtin_amdgcn_raw_buffer_load_b32(r, off, 0, SCX);
  return __builtin_bit_cast(float, v);
}
__device__ __forceinline__ void st_f(rsrc_t r, int off, float v){
  __builtin_amdgcn_raw_buffer_store_b32(__builtin_bit_cast(unsigned, v), r, off, 0, SCX);
}
__device__ __forceinline__ void st_f4(rsrc_t r, int off, floatx4 v){
  __builtin_amdgcn_raw_buffer_store_b128(v, r, off, 0, SCX);
}

__device__ __forceinline__ float sigm(float x){ return 1.0f/(1.0f + __expf(-x)); }
__device__ __forceinline__ float tanh_f(float x){ return 1.0f - 2.0f/(1.0f + __expf(2.0f*x)); }

// Per-wave release: drain THIS wave's stores (vmcnt is per-wave; h-stores
// acked at own-XCD L2, opart too), then lane 0 publishes the phase number
// at agent scope (LIC). No workgroup rendezvous.
__device__ __forceinline__ void xsignal(int grp, int s4w, unsigned target,
                                        int lane){
  __builtin_amdgcn_s_waitcnt(0);
  if (lane == 0)
    __hip_atomic_store(&g_flags[grp*128 + s4w], target, __ATOMIC_RELAXED,
                       __HIP_MEMORY_SCOPE_AGENT);
}

// Per-wave acquire: every wave polls the group's 128 wave-flags (2 per
// lane), ballot across the wave. No trailing __syncthreads (the staging
// barrier inside do_phase16 is the only WG sync). Monotone phases.
__device__ __forceinline__ void xwait(int grp, unsigned target,
                                      bool& alive, int lane){
  if (!alive) return;
  int guard = 0;
  for (;;){
    unsigned f0 = __hip_atomic_load(&g_flags[grp*128 + lane],
                                    __ATOMIC_RELAXED, __HIP_MEMORY_SCOPE_AGENT);
    unsigned f1 = __hip_atomic_load(&g_flags[grp*128 + 64 + lane],
                                    __ATOMIC_RELAXED, __HIP_MEMORY_SCOPE_AGENT);
    bool ok = (f0 >= target) && (f1 >= target);
    if (__ballot(ok) == 0xFFFFFFFFFFFFFFFFull) break;
    __builtin_amdgcn_s_sleep(1);
    if (++guard > (1<<22)){ alive = false; break; }
  }
}

// One 16-row group phase. Stages group h slices L2->LDS (swizzled, 64B
// chunks/thread), MFMAs M=16 from LDS vs VGPR weights. DOL1: h1=lstm(x,
// h1prev); XSEL 0 = x from seqT, 1 = x from o-partial gather (+bl). DOL2:
// h2=lstm(h1r,h2prev) + full-line o-partial store (zero-filled top half).
template<bool DOL1, bool DOL2, int XSEL>
__device__ __forceinline__ void do_phase16(
    rsrc_t rh1, rsrc_t rh2, rsrc_t rop, rsrc_t rsq,
    int o_h1r, int o_h2r, int o_h1w, int o_h2w,
    int o_x, int xs_t, float xadd, int t_out,
    _Float16* __restrict__ lA1, _Float16* __restrict__ lA2,
    const half8 (&wf1)[16], const half8 (&wfx)[16], const half8 (&wfh)[16],
    float b1, float b2, float wx, float wl,
    float (&c1v)[4], float (&c2v)[4],
    int rowbase, int jbase, int jwave, int tid, int ln, int quad, int hcb)
{
  // ---- stage A slices (16 rows x 512 fp16) from L2 into swizzled LDS ----
  // 256 threads: row = tid>>4, each thread owns a contiguous 64B chunk.
  {
    const int row = tid >> 4, c16 = tid & 15;
    const int gb1 = o_h1r + (rowbase + row)*H*2;
    const int gb2 = o_h2r + (rowbase + row)*H*2;
    #pragma unroll
    for (int g4 = 0; g4 < 4; ++g4){
      const int gran = c16*4 + g4;
      const int loff = row*512 + ((gran ^ (row&7)) << 3);
      half8 v = ld_h8(rh1, gb1 + gran*16);
      *(half8*)(lA1 + loff) = v;
      if (DOL2){
        half8 u = ld_h8(rh2, gb2 + gran*16);
        *(half8*)(lA2 + loff) = u;
      }
    }
  }

  float xv[4];
  if (DOL1){
    if (XSEL == 0){
      floatx4 x4 = ld_f4(rsq, o_x + (rowbase + quad*4)*4);
      #pragma unroll
      for (int r=0; r<4; ++r) xv[r] = x4[r] + xadd;
    } else {
      #pragma unroll
      for (int r=0; r<4; ++r){
        const int lr = quad*4 + r;            // group-local row
        float s = 0.f;
        #pragma unroll
        for (int cc=0; cc<8; ++cc){
          const int j = jbase + ln*8 + cc;    // 128 owners of this group
          s += ld_f(rop, ((j*TP + xs_t)*32 + lr)*4);
        }
        s += __shfl_xor(s, 1, 64);
        s += __shfl_xor(s, 2, 64);
        s += __shfl_xor(s, 4, 64);
        s += __shfl_xor(s, 8, 64);
        xv[r] = s + xadd;
      }
    }
  }
  __syncthreads();   // staging visible WG-wide (the ONLY per-phase WG sync)

  floatx4 zf4 = {0.f,0.f,0.f,0.f};
  floatx4 z1 = zf4, z2 = zf4;

  #pragma unroll
  for (int kk = 0; kk < 16; ++kk){
    const int sw = (((kk*4 + quad) ^ (ln&7)) << 3);
    half8 a1 = *(const half8*)(lA1 + ln*512 + sw);
    if (DOL1)
      z1 = MFMA(a1, wf1[kk], z1);
    if (DOL2){
      z2 = MFMA(a1, wfx[kk], z2);
      half8 a2 = *(const half8*)(lA2 + ln*512 + sw);
      z2 = MFMA(a2, wfh[kk], z2);
    }
  }

  const bool l4 = (ln < 4);
  const bool evn = ((ln & 1) == 0);
  if (DOL1){
    #pragma unroll
    for (int r=0; r<4; ++r){
      const int row = rowbase + quad*4 + r;
      float z = z1[r] + xv[r]*wx + b1;
      float p4  = __shfl_xor(z, 4, 64);
      float p8  = __shfl_xor(z, 8, 64);
      float p12 = __shfl_xor(z, 12, 64);
      float ig = sigm(z), fg = sigm(p4), og = sigm(p8), gg = tanh_f(p12);
      float c = fg*c1v[r] + ig*gg;
      c1v[r] = c;
      float h = og*tanh_f(c);
      unsigned hu = (unsigned)__builtin_bit_cast(unsigned short, (_Float16)h);
      unsigned pn = (unsigned)__shfl_xor((int)hu, 1, 64);
      if (l4 && evn)
        st_f(rh1, o_h1w + (row*H + hcb + ln)*2,
             __builtin_bit_cast(float, hu | (pn<<16)));
    }
  }
  if (DOL2){
    floatx4 po4;
    #pragma unroll
    for (int r=0; r<4; ++r){
      const int row = rowbase + quad*4 + r;
      float z = z2[r] + b2;
      float p4  = __shfl_xor(z, 4, 64);
      float p8  = __shfl_xor(z, 8, 64);
      float p12 = __shfl_xor(z, 12, 64);
      float ig = sigm(z), fg = sigm(p4), og = sigm(p8), gg = tanh_f(p12);
      float c = fg*c2v[r] + ig*gg;
      c2v[r] = c;
      float h = og*tanh_f(c);
      unsigned hu = (unsigned)__builtin_bit_cast(unsigned short, (_Float16)h);
      unsigned pn = (unsigned)__shfl_xor((int)hu, 1, 64);
      if (l4 && evn)
        st_f(rh2, o_h2w + (row*H + hcb + ln)*2,
             __builtin_bit_cast(float, hu | (pn<<16)));
      float po = l4 ? h*wl : 0.f;
      po += __shfl_xor(po, 1, 64);
      po += __shfl_xor(po, 2, 64);
      po4[r] = po;                  // valid in ln==0 lanes
    }
    if (ln == 0){                   // full 128B line per wave per t
      const int base = ((jwave*TP + t_out)*32)*4;
      st_f4(rop, base + quad*16, po4);
      st_f4(rop, base + 64 + quad*16, zf4);   // zero-fill rows 16..31
    }
  }
}

__global__ void reset_kernel(){
  for (int i = threadIdx.x; i < 16*128; i += 512)
    __hip_atomic_store(&g_flags[i], 0u, __ATOMIC_RELAXED,
                       __HIP_MEMORY_SCOPE_AGENT);
}

__global__ __launch_bounds__(BLOCK, 1) void sinernn_kernel(
    const float* __restrict__ seq, const float* __restrict__ Wx1,
    const float* __restrict__ bx1, const float* __restrict__ Wh1,
    const float* __restrict__ bh1, const float* __restrict__ Wx2,
    const float* __restrict__ bx2, const float* __restrict__ Wh2,
    const float* __restrict__ bh2, const float* __restrict__ Wl,
    const float* __restrict__ bl,  float* __restrict__ out)
{
  __shared__ __attribute__((aligned(16))) _Float16 lA1A[RPG*512];  // 16 KB
  __shared__ __attribute__((aligned(16))) _Float16 lA2A[RPG*512];  // 16 KB
  __shared__ __attribute__((aligned(16))) _Float16 lA1B[RPG*512];  // 16 KB
  __shared__ __attribute__((aligned(16))) _Float16 lA2B[RPG*512];  // 16 KB

  const int tid  = threadIdx.x;
  const int wg   = blockIdx.x;
  const int xcd  = wg & 7;
  const int slot = wg >> 3;            // 0..31
  const int ga   = xcd, gb = xcd + 8;  // this WG's two groups
  const int w    = tid >> 6;
  const int lane = tid & 63;
  const int ln   = lane & 15;
  const int quad = lane >> 4;
  const int rbA  = ga*RPG, rbB = gb*RPG;
  const int hcb  = slot*16 + w*4;      // this wave's 4 h-cols
  const int s4w  = slot*4 + w;         // per-wave flag slot within group
  const int jA   = ga*128 + s4w;
  const int jB   = gb*128 + s4w;

  rsrc_t rh1 = mkrsrc((void*)&g_h1[0]);
  rsrc_t rh2 = mkrsrc((void*)&g_h2[0]);
  rsrc_t rop = mkrsrc((void*)&g_opart[0]);
  rsrc_t rsq = mkrsrc((void*)&g_seqT[0]);

  // gate-col: gate = ln>>2, h-col = hcb + (ln&3)
  const int gc = (ln>>2)*H + hcb + (ln&3);

  // ---- prologue: seqT transpose (16 t-values x 16 rows x 2 groups) ----
  for (int i = tid; i < 2*16*16; i += BLOCK){
    int g = i >> 8;
    int t = slot*16 + ((i>>4)&15), j = i & 15;
    int row = (g ? rbB : rbA) + j;
    st_f(rsq, (t*BATCH + row)*4, seq[row*T_SEQ + t]);
  }
  // zero h(-1) (buffer 1) for both groups' rows; redundant across slots
  for (int i = tid; i < RPG*H/2; i += BLOCK){
    st_f(rh1, HBYTES + rbA*H*2 + i*4, 0.f);
    st_f(rh2, HBYTES + rbA*H*2 + i*4, 0.f);
    st_f(rh1, HBYTES + rbB*H*2 + i*4, 0.f);
    st_f(rh2, HBYTES + rbB*H*2 + i*4, 0.f);
  }

  // ---- stage all three weight slices into VGPRs (192/lane, shared) ----
  half8 wf1[16], wfx[16], wfh[16];
  #pragma unroll
  for (int kk = 0; kk < 16; ++kk){
    #pragma unroll
    for (int j = 0; j < 8; ++j){
      const int k = kk*32 + quad*8 + j;
      wf1[kk][j] = (_Float16)Wh1[k*G4H + gc];
      wfx[kk][j] = (_Float16)Wx2[k*G4H + gc];
      wfh[kk][j] = (_Float16)Wh2[k*G4H + gc];
    }
  }
  const float b1 = bx1[gc] + bh1[gc];
  const float b2 = bx2[gc] + bh2[gc];
  const float wx = Wx1[gc];
  const float wl = (ln < 4) ? Wl[hcb + (ln&3)] : 0.f;
  const float blv = bl[0];

  float c1A[4] = {0.f,0.f,0.f,0.f}, c2A[4] = {0.f,0.f,0.f,0.f};
  float c1B[4] = {0.f,0.f,0.f,0.f}, c2B[4] = {0.f,0.f,0.f,0.f};

  bool alive = true;
  unsigned cur = 1;
  // prologue visible group-wide (each wave's flag covers its own stores;
  // consumers require ALL 128 wave-flags)
  xsignal(ga, s4w, 1, lane);
  xsignal(gb, s4w, 1, lane);

  // ---- main: round p = {phaseA(p), phaseB(p)}; phase computes h1(p),h2(p-1)
  for (int p = 0; p < T_SEQ; ++p){
    const int b_h1r = ((p+1)&1)*HBYTES;
    const int b_h1w = (p&1)*HBYTES;
    const int b_h2r = (p&1)*HBYTES;
    const int b_h2w = ((p+1)&1)*HBYTES;

    xwait(ga, cur, alive, lane);
    if (p == 0)
      do_phase16<true,false,0>(rh1,rh2,rop,rsq, b_h1r,0, b_h1w,0,
                               0, 0, 0.f, -1, lA1A, lA2A, wf1,wfx,wfh,
                               b1,b2,wx,wl, c1A,c2A,
                               rbA, ga*128, jA, tid, ln, quad, hcb);
    else
      do_phase16<true,true,0>(rh1,rh2,rop,rsq, b_h1r,b_h2r, b_h1w,b_h2w,
                              p*BATCH*4, 0, 0.f, p-1, lA1A, lA2A, wf1,wfx,wfh,
                              b1,b2,wx,wl, c1A,c2A,
                              rbA, ga*128, jA, tid, ln, quad, hcb);
    xsignal(ga, s4w, cur+1, lane);

    xwait(gb, cur, alive, lane);
    if (p == 0)
      do_phase16<true,false,0>(rh1,rh2,rop,rsq, b_h1r,0, b_h1w,0,
                               0, 0, 0.f, -1, lA1B, lA2B, wf1,wfx,wfh,
                               b1,b2,wx,wl, c1B,c2B,
                               rbB, gb*128, jB, tid, ln, quad, hcb);
    else
      do_phase16<true,true,0>(rh1,rh2,rop,rsq, b_h1r,b_h2r, b_h1w,b_h2w,
                              p*BATCH*4, 0, 0.f, p-1, lA1B, lA2B, wf1,wfx,wfh,
                              b1,b2,wx,wl, c1B,c2B,
                              rbB, gb*128, jB, tid, ln, quad, hcb);
    xsignal(gb, s4w, cur+1, lane);
    ++cur;
  }

  // ---- drain + autoregressive predict (one phase per group per round) ----
  for (int s = T_SEQ-1; s < TP; ++s){
    xwait(ga, cur, alive, lane);
    do_phase16<false,true,0>(rh1,rh2,rop,rsq, (s&1)*HBYTES,((s+1)&1)*HBYTES,
                             0,(s&1)*HBYTES, 0, 0, 0.f, s,
                             lA1A, lA2A, wf1,wfx,wfh, b1,b2,wx,wl, c1A,c2A,
                             rbA, ga*128, jA, tid, ln, quad, hcb);
    xsignal(ga, s4w, cur+1, lane);
    xwait(gb, cur, alive, lane);
    do_phase16<false,true,0>(rh1,rh2,rop,rsq, (s&1)*HBYTES,((s+1)&1)*HBYTES,
                             0,(s&1)*HBYTES, 0, 0, 0.f, s,
                             lA1B, lA2B, wf1,wfx,wfh, b1,b2,wx,wl, c1B,c2B,
                             rbB, gb*128, jB, tid, ln, quad, hcb);
    xsignal(gb, s4w, cur+1, lane);
    ++cur;

    if (s + 1 < TP){
      xwait(ga, cur, alive, lane);
      do_phase16<true,false,1>(rh1,rh2,rop,rsq, (s&1)*HBYTES,0,
                               ((s+1)&1)*HBYTES,0, 0, s, blv, -1,
                               lA1A, lA2A, wf1,wfx,wfh, b1,b2,wx,wl, c1A,c2A,
                               rbA, ga*128, jA, tid, ln, quad, hcb);
      xsignal(ga, s4w, cur+1, lane);
      xwait(gb, cur, alive, lane);
      do_phase16<true,false,1>(rh1,rh2,rop,rsq, (s&1)*HBYTES,0,
                               ((s+1)&1)*HBYTES,0, 0, s, blv, -1,
                               lA1B, lA2B, wf1,wfx,wfh, b1,b2,wx,wl, c1B,c2B,
                               rbB, gb*128, jB, tid, ln, quad, hcb);
      xsignal(gb, s4w, cur+1, lane);
      ++cur;
    }
  }
  // final: all group waves (incl. co-waves of this WG) completed all phases
  xwait(ga, cur, alive, lane);
  xwait(gb, cur, alive, lane);

  // ---- epilogue: out[row][t] = sum over the group's 128 (slot',w') ----
  {
    float* lred = (float*)lA1A;          // reuse staging LDS
    const int row = tid & 15, part = tid >> 4;   // 16 parts x 8 j's
    for (int gsel = 0; gsel < 2; ++gsel){
      const int jb = (gsel ? gb : ga)*128;
      const int rb = (gsel ? rbB : rbA);
      for (int i = 0; i < 17; ++i){
        const int t = slot + i*32;
        float s = 0.f;
        #pragma unroll
        for (int q = 0; q < 8; ++q){
          const int j = jb + part*8 + q;
          s += ld_f(rop, ((j*TP + t)*32 + row)*4);
        }
        __syncthreads();
        lred[part*16 + row] = s;
        __syncthreads();
        if (tid < 16){
          float o = 0.f;
          #pragma unroll
          for (int p2 = 0; p2 < 16; ++p2) o += lred[p2*16 + tid];
          out[(rb + tid)*TP + t] = o + blv;
        }
      }
    }
  }
}

extern "C" void kernel_launch(void* const* d_in, const int* in_sizes, int n_in,
                              void* d_out, int out_size, void* d_ws, size_t ws_size,
                              hipStream_t stream) {
  const float* seq = (const float*)d_in[0];
  // d_in[1] = predict (=32, hardcoded)
  const float* Wx1 = (const float*)d_in[2];
  const float* bx1 = (const float*)d_in[3];
  const float* Wh1 = (const float*)d_in[4];
  const float* bh1 = (const float*)d_in[5];
  const float* Wx2 = (const float*)d_in[6];
  const float* bx2 = (const float*)d_in[7];
  const float* Wh2 = (const float*)d_in[8];
  const float* bh2 = (const float*)d_in[9];
  const float* Wl  = (const float*)d_in[10];
  const float* bl  = (const float*)d_in[11];
  float* out = (float*)d_out;

  reset_kernel<<<1, 512, 0, stream>>>();

  sinernn_kernel<<<dim3(GRID), dim3(BLOCK), 0, stream>>>(
      seq, Wx1, bx1, Wh1, bh1, Wx2, bx2, Wh2, bh2, Wl, bl, out);
}